// Round 2
// baseline (1218.398 us; speedup 1.0000x reference)
//
#include <hip/hip_runtime.h>
#include <math.h>

// FFT convolution: y[b,d,:] = (h[d] (*) x[b,d])[0:L] + x[b,d,:]*B[d]
// N=8192 packed-complex FFT per row in 64KB LDS. Register-blocked
// 4-stage passes (3 LDS round trips per FFT), twiddles via one sincos +
// squaring chain + compile-time 8th-root constants, XOR bank swizzle,
// fused middle stage (fwd stage12 + untangle + pointwise + inv stage0).

#define FFT_N  8192
#define LOG_N  13
#define SEQ_L  8192
#define DIM_D  1024
#define NTHR   512

__device__ __forceinline__ float2 cadd(float2 a, float2 b){ return make_float2(a.x+b.x, a.y+b.y); }
__device__ __forceinline__ float2 csub(float2 a, float2 b){ return make_float2(a.x-b.x, a.y-b.y); }
__device__ __forceinline__ float2 cmul(float2 a, float2 b){ return make_float2(a.x*b.x - a.y*b.y, a.x*b.y + a.y*b.x); }
__device__ __forceinline__ int rev13(int k){ return (int)(__brev((unsigned)k) >> 19); }
// bank-conflict swizzle: spread bank-pair (i&15) with higher bits. bijective.
__device__ __forceinline__ int SW(int i){ return i ^ ((i >> 5) & 15) ^ ((i >> 9) & 15); }

// ---- 4 radix-2 DIF stages in registers. v[k]: k = owned 4 bits, bit3 = highest.
// w = exp(-i*pi*r/2^b) base twiddle for first stage; squared between stages.
__device__ __forceinline__ void dif_pass4(float2 v[16], float2 w){
    {   // sigma0: bit3, const = exp(-i pi m/8)
        constexpr float c8c[8] = {1.f, 0.92387953251f, 0.70710678119f, 0.38268343236f, 0.f, -0.38268343236f, -0.70710678119f, -0.92387953251f};
        constexpr float c8s[8] = {0.f, -0.38268343236f, -0.70710678119f, -0.92387953251f, -1.f, -0.92387953251f, -0.70710678119f, -0.38268343236f};
        #pragma unroll
        for (int m = 0; m < 8; ++m){
            float2 tw = cmul(make_float2(c8c[m], c8s[m]), w);
            float2 u = v[m], t = v[m+8];
            v[m] = cadd(u,t);
            v[m+8] = cmul(csub(u,t), tw);
        }
    }
    w = cmul(w,w);
    {   // sigma1: bit2, const = exp(-i pi m/4)
        constexpr float c4c[4] = {1.f, 0.70710678119f, 0.f, -0.70710678119f};
        constexpr float c4s[4] = {0.f, -0.70710678119f, -1.f, -0.70710678119f};
        #pragma unroll
        for (int h = 0; h < 16; h += 8)
            #pragma unroll
            for (int m = 0; m < 4; ++m){
                float2 tw = cmul(make_float2(c4c[m], c4s[m]), w);
                float2 u = v[h+m], t = v[h+m+4];
                v[h+m] = cadd(u,t);
                v[h+m+4] = cmul(csub(u,t), tw);
            }
    }
    w = cmul(w,w);
    // sigma2: bit1, const = {1, -i}
    #pragma unroll
    for (int q = 0; q < 16; q += 4)
        #pragma unroll
        for (int m = 0; m < 2; ++m){
            float2 tw = (m == 0) ? w : make_float2(w.y, -w.x);   // (-i)*w
            float2 u = v[q+m], t = v[q+m+2];
            v[q+m] = cadd(u,t);
            v[q+m+2] = cmul(csub(u,t), tw);
        }
    w = cmul(w,w);
    // sigma3: bit0, const = 1
    #pragma unroll
    for (int e = 0; e < 16; e += 2){
        float2 u = v[e], t = v[e+1];
        v[e] = cadd(u,t);
        v[e+1] = cmul(csub(u,t), w);
    }
}

// ---- 4 radix-2 DIT (inverse, +i) stages in registers. k bit0 = lowest stage.
// w3 = base twiddle of the LAST (highest) stage; chained down by squaring.
__device__ __forceinline__ void dit_pass4(float2 v[16], float2 w3){
    float2 w2 = cmul(w3,w3), w1 = cmul(w2,w2), w0 = cmul(w1,w1);
    // sigma0: bit0
    #pragma unroll
    for (int e = 0; e < 16; e += 2){
        float2 t = cmul(v[e+1], w0);
        float2 u = v[e];
        v[e] = cadd(u,t); v[e+1] = csub(u,t);
    }
    // sigma1: bit1, const = {1, +i}
    #pragma unroll
    for (int q = 0; q < 16; q += 4)
        #pragma unroll
        for (int m = 0; m < 2; ++m){
            float2 tw = (m == 0) ? w1 : make_float2(-w1.y, w1.x); // (+i)*w
            float2 t = cmul(v[q+m+2], tw);
            float2 u = v[q+m];
            v[q+m] = cadd(u,t); v[q+m+2] = csub(u,t);
        }
    {   // sigma2: bit2, const = exp(+i pi m/4)
        constexpr float c4c[4] = {1.f, 0.70710678119f, 0.f, -0.70710678119f};
        constexpr float c4s[4] = {0.f, 0.70710678119f, 1.f, 0.70710678119f};
        #pragma unroll
        for (int h = 0; h < 16; h += 8)
            #pragma unroll
            for (int m = 0; m < 4; ++m){
                float2 tw = cmul(make_float2(c4c[m], c4s[m]), w2);
                float2 t = cmul(v[h+m+4], tw);
                float2 u = v[h+m];
                v[h+m] = cadd(u,t); v[h+m+4] = csub(u,t);
            }
    }
    {   // sigma3: bit3, const = exp(+i pi m/8)
        constexpr float c8c[8] = {1.f, 0.92387953251f, 0.70710678119f, 0.38268343236f, 0.f, -0.38268343236f, -0.70710678119f, -0.92387953251f};
        constexpr float c8s[8] = {0.f, 0.38268343236f, 0.70710678119f, 0.92387953251f, 1.f, 0.92387953251f, 0.70710678119f, 0.38268343236f};
        #pragma unroll
        for (int m = 0; m < 8; ++m){
            float2 tw = cmul(make_float2(c8c[m], c8s[m]), w3);
            float2 t = cmul(v[m+8], tw);
            float2 u = v[m];
            v[m] = cadd(u,t); v[m+8] = csub(u,t);
        }
    }
}

// forward stages 0..11 on LDS (leaves stage-11 output in LDS, bitrev-pending)
__device__ __forceinline__ void fwd_fft12(float2* z, int tid){
    float2 v[16];
    float sn, cs;
    // pass A: stages 0-3, owned bits 12..9. i = k<<9 | tid
    __sincosf(-(float)M_PI * (float)tid * (1.0f/4096.0f), &sn, &cs);
    float2 base = make_float2(cs, sn);
    #pragma unroll
    for (int k = 0; k < 16; ++k) v[k] = z[SW((k<<9) | tid)];
    dif_pass4(v, base);
    #pragma unroll
    for (int k = 0; k < 16; ++k) z[SW((k<<9) | tid)] = v[k];
    __syncthreads();
    // pass B: stages 4-7, owned bits 8..5. i = hi<<9 | k<<5 | lo
    const int hi = tid >> 5, lo = tid & 31;
    __sincosf(-(float)M_PI * (float)lo * (1.0f/256.0f), &sn, &cs);
    base = make_float2(cs, sn);
    #pragma unroll
    for (int k = 0; k < 16; ++k) v[k] = z[SW((hi<<9) | (k<<5) | lo)];
    dif_pass4(v, base);
    #pragma unroll
    for (int k = 0; k < 16; ++k) z[SW((hi<<9) | (k<<5) | lo)] = v[k];
    __syncthreads();
    // pass C: stages 8-11, owned bits 4..1. i = h2<<5 | k<<1 | b0
    const int h2 = tid >> 1, b0 = tid & 1;
    base = b0 ? make_float2(0.98078528040f, -0.19509032202f)   // exp(-i pi/16)
              : make_float2(1.f, 0.f);
    #pragma unroll
    for (int k = 0; k < 16; ++k) v[k] = z[SW((h2<<5) | (k<<1) | b0)];
    dif_pass4(v, base);
    #pragma unroll
    for (int k = 0; k < 16; ++k) z[SW((h2<<5) | (k<<1) | b0)] = v[k];
    __syncthreads();
}

// real-FFT untangle: from Z[rev(p)], Z[rev(N-p)] produce A=E+tO, G=E-tO
__device__ __forceinline__ void untangle(float2 zk, float2 znk, float2 t, float2& A, float2& G){
    float2 E  = make_float2(0.5f*(zk.x+znk.x), 0.5f*(zk.y-znk.y));
    float2 O  = make_float2(0.5f*(zk.y+znk.y), -0.5f*(zk.x-znk.x));
    float2 tO = cmul(t, O);
    A = cadd(E, tO); G = csub(E, tO);
}

// untangle x, multiply with H (Ah,Gh), repack packed-inverse spectrum pair
__device__ __forceinline__ void pointmul(float2 zk, float2 znk, float2 t,
                                         float2 Ah, float2 Gh, float invN,
                                         float2& Wp, float2& Wm){
    float2 Xp, Xm; untangle(zk, znk, t, Xp, Xm);
    float2 Cp = cmul(Ah, Xp), Cm = cmul(Gh, Xm);
    float2 S  = make_float2(0.5f*(Cp.x+Cm.x), 0.5f*(Cp.y+Cm.y));
    float2 Dd = make_float2(0.5f*(Cp.x-Cm.x), 0.5f*(Cp.y-Cm.y));
    float2 u  = make_float2(t.y*Dd.x - t.x*Dd.y, t.y*Dd.y + t.x*Dd.x); // i*conj(t)*Dd
    Wp = make_float2((S.x+u.x)*invN, (S.y+u.y)*invN);
    Wm = make_float2((S.x-u.x)*invN, -((S.y-u.y)*invN));
}

__global__ __launch_bounds__(NTHR, 4)
void fftconv_kernel(const float* __restrict__ h,
                    const float* __restrict__ x,
                    const float* __restrict__ Bv,
                    float* __restrict__ y)
{
    __shared__ float2 z[FFT_N];   // 64 KB
    const int tid = (int)threadIdx.x;
    const int d   = (int)blockIdx.x;
    const int b   = (int)blockIdx.y;

    const float Bd = Bv[d];
    const float2* hrow = (const float2*)(h + (size_t)d * SEQ_L);
    const float2* xrow = (const float2*)(x + ((size_t)b * DIM_D + (size_t)d) * SEQ_L);
    float2*       yrow = (float2*)(y + ((size_t)b * DIM_D + (size_t)d) * SEQ_L);
    const float invN = 1.0f / (float)FFT_N;

    // ================= h phase =================
    #pragma unroll
    for (int j = 0; j < 8; ++j){
        int n = tid + NTHR * j;
        z[SW(n)] = hrow[n];
        z[SW(n + FFT_N/2)] = make_float2(0.f, 0.f);
    }
    __syncthreads();
    fwd_fft12(z, tid);

    // fused fwd-stage12 + untangle -> H spectrum in registers.
    // group g: quad of spectral p {g, 4096-g, 4096+g, 8192-g}, bitrev
    // addresses {a, a+1, c, c+1}; a = rev(g), c = rev(4096-g).
    float2 Ah1[4], Gh1[4], Ah2[4], Gh2[4], Ah3, Gh3;
    #pragma unroll
    for (int q = 0; q < 4; ++q){
        int g = tid + NTHR * q;
        if (g == 0){
            float2 z0 = z[SW(0)], z1 = z[SW(1)], z2 = z[SW(2)], z3 = z[SW(3)];
            float2 Z0 = cadd(z0,z1), Z1 = csub(z0,z1), Z2 = cadd(z2,z3), Z3 = csub(z2,z3);
            untangle(Z0, Z0, make_float2(1.f, 0.f), Ah1[0], Gh1[0]);                       // p=0
            untangle(Z2, Z3, make_float2(0.70710678119f, -0.70710678119f), Ah2[0], Gh2[0]);// p=2048
            untangle(Z1, Z1, make_float2(0.f, -1.f), Ah3, Gh3);                            // p=4096
        } else {
            int a = rev13(g), c = rev13(4096 - g);
            float2 za = z[SW(a)], zb = z[SW(a+1)], zc = z[SW(c)], zd = z[SW(c+1)];
            float2 Z12a = cadd(za,zb), Z12b = csub(za,zb);
            float2 Z12c = cadd(zc,zd), Z12d = csub(zc,zd);
            float sn, cs; __sincosf(-(float)M_PI * (float)g * (1.0f/8192.0f), &sn, &cs);
            float2 t1 = make_float2(cs, sn);            // exp(-i pi g/8192)
            float2 t2 = make_float2(-sn, -cs);          // exp(-i pi (4096-g)/8192)
            untangle(Z12a, Z12d, t1, Ah1[q], Gh1[q]);   // pair (g, 8192-g)
            untangle(Z12c, Z12b, t2, Ah2[q], Gh2[q]);   // pair (4096-g, 4096+g)
        }
    }
    __syncthreads();

    // ================= x phase =================
    #pragma unroll
    for (int j = 0; j < 8; ++j){
        int n = tid + NTHR * j;
        z[SW(n)] = xrow[n];
        z[SW(n + FFT_N/2)] = make_float2(0.f, 0.f);
    }
    __syncthreads();
    fwd_fft12(z, tid);

    // fused middle: fwd stage12 + untangle + multiply + repack + inv stage0.
    // per-thread quad is closed: read & write same 4 addresses, no barrier inside.
    #pragma unroll
    for (int q = 0; q < 4; ++q){
        int g = tid + NTHR * q;
        if (g == 0){
            float2 z0 = z[SW(0)], z1 = z[SW(1)], z2 = z[SW(2)], z3 = z[SW(3)];
            float2 Z0 = cadd(z0,z1), Z1 = csub(z0,z1), Z2 = cadd(z2,z3), Z3 = csub(z2,z3);
            float2 W0, W0b, W1, W1b, W2, W3;
            pointmul(Z0, Z0, make_float2(1.f, 0.f),  Ah1[0], Gh1[0], invN, W0, W0b);
            pointmul(Z1, Z1, make_float2(0.f, -1.f), Ah3,    Gh3,    invN, W1, W1b);
            pointmul(Z2, Z3, make_float2(0.70710678119f, -0.70710678119f), Ah2[0], Gh2[0], invN, W2, W3);
            z[SW(0)] = cadd(W0, W1);
            z[SW(1)] = csub(W0, W1);
            z[SW(2)] = cadd(W2, W3);
            z[SW(3)] = csub(W2, W3);
        } else {
            int a = rev13(g), c = rev13(4096 - g);
            float2 za = z[SW(a)], zb = z[SW(a+1)], zc = z[SW(c)], zd = z[SW(c+1)];
            float2 Z12a = cadd(za,zb), Z12b = csub(za,zb);
            float2 Z12c = cadd(zc,zd), Z12d = csub(zc,zd);
            float sn, cs; __sincosf(-(float)M_PI * (float)g * (1.0f/8192.0f), &sn, &cs);
            float2 t1 = make_float2(cs, sn), t2 = make_float2(-sn, -cs);
            float2 Wp1, Wm1, Wp2, Wm2;
            pointmul(Z12a, Z12d, t1, Ah1[q], Gh1[q], invN, Wp1, Wm1);
            pointmul(Z12c, Z12b, t2, Ah2[q], Gh2[q], invN, Wp2, Wm2);
            // inverse stage 0 (pairs (a,a+1),(c,c+1), W=1)
            z[SW(a)]   = cadd(Wp1, Wm2);
            z[SW(a+1)] = csub(Wp1, Wm2);
            z[SW(c)]   = cadd(Wp2, Wm1);
            z[SW(c+1)] = csub(Wp2, Wm1);
        }
    }
    __syncthreads();

    // ================= inverse stages 1..12 =================
    {
        float2 v[16];
        float sn, cs;
        const int h2 = tid >> 1, b0 = tid & 1, hi = tid >> 5, lo = tid & 31;
        // pass I1: stages 1-4, bits 4..1
        float2 w3 = b0 ? make_float2(0.98078528040f, 0.19509032202f)  // exp(+i pi/16)
                       : make_float2(1.f, 0.f);
        #pragma unroll
        for (int k = 0; k < 16; ++k) v[k] = z[SW((h2<<5) | (k<<1) | b0)];
        dit_pass4(v, w3);
        #pragma unroll
        for (int k = 0; k < 16; ++k) z[SW((h2<<5) | (k<<1) | b0)] = v[k];
        __syncthreads();
        // pass I2: stages 5-8, bits 8..5
        __sincosf((float)M_PI * (float)lo * (1.0f/256.0f), &sn, &cs);
        w3 = make_float2(cs, sn);
        #pragma unroll
        for (int k = 0; k < 16; ++k) v[k] = z[SW((hi<<9) | (k<<5) | lo)];
        dit_pass4(v, w3);
        #pragma unroll
        for (int k = 0; k < 16; ++k) z[SW((hi<<9) | (k<<5) | lo)] = v[k];
        __syncthreads();
        // pass I3: stages 9-12, bits 12..9
        __sincosf((float)M_PI * (float)tid * (1.0f/4096.0f), &sn, &cs);
        w3 = make_float2(cs, sn);
        #pragma unroll
        for (int k = 0; k < 16; ++k) v[k] = z[SW((k<<9) | tid)];
        dit_pass4(v, w3);
        #pragma unroll
        for (int k = 0; k < 16; ++k) z[SW((k<<9) | tid)] = v[k];
        __syncthreads();
    }

    // ================= epilogue =================
    #pragma unroll
    for (int j = 0; j < 8; ++j){
        int n = tid + NTHR * j;
        float2 wv = z[SW(n)];
        float2 xv = xrow[n];
        yrow[n] = make_float2(wv.x + xv.x * Bd, wv.y + xv.y * Bd);
    }
}

extern "C" void kernel_launch(void* const* d_in, const int* in_sizes, int n_in,
                              void* d_out, int out_size, void* d_ws, size_t ws_size,
                              hipStream_t stream) {
    const float* h  = (const float*)d_in[0];
    const float* x  = (const float*)d_in[1];
    const float* Bv = (const float*)d_in[2];
    float* y = (float*)d_out;

    const int bsz = out_size / (DIM_D * SEQ_L);   // = 4
    dim3 grid(DIM_D, bsz, 1);
    dim3 block(NTHR, 1, 1);
    hipLaunchKernelGGL(fftconv_kernel, grid, block, 0, stream, h, x, Bv, y);
}

// Round 3
// 403.297 us; speedup vs baseline: 3.0211x; 3.0211x over previous
//
#include <hip/hip_runtime.h>
#include <math.h>

// FFT convolution: y[b,d,:] = (h[d] (*) x[b,d])[0:L] + x[b,d,:]*B[d]
// N=8192 packed-complex FFT per row in 64KB LDS. Register-blocked
// 4-stage passes, twiddles via one sincos + squaring chain, XOR bank
// swizzle, fused middle (fwd stage12 + untangle + pointwise + inv stage0).
// Two-kernel split: H spectra precomputed once per d into d_ws (kernel A),
// x-phase kernel B streams them at the pointwise stage. No launch-bounds
// occupancy clamp (R2's clamp caused scratch spills -> 3.9GB HBM traffic).

#define FFT_N  8192
#define LOG_N  13
#define SEQ_L  8192
#define DIM_D  1024
#define NTHR   512

__device__ __forceinline__ float2 cadd(float2 a, float2 b){ return make_float2(a.x+b.x, a.y+b.y); }
__device__ __forceinline__ float2 csub(float2 a, float2 b){ return make_float2(a.x-b.x, a.y-b.y); }
__device__ __forceinline__ float2 cmul(float2 a, float2 b){ return make_float2(a.x*b.x - a.y*b.y, a.x*b.y + a.y*b.x); }
__device__ __forceinline__ int rev13(int k){ return (int)(__brev((unsigned)k) >> 19); }
// bank-conflict swizzle: spread bank-pair (i&15) with higher bits. bijective.
__device__ __forceinline__ int SW(int i){ return i ^ ((i >> 5) & 15) ^ ((i >> 9) & 15); }

// ---- 4 radix-2 DIF stages in registers. v[k]: k = owned 4 bits, bit3 = highest.
__device__ __forceinline__ void dif_pass4(float2 v[16], float2 w){
    {   constexpr float c8c[8] = {1.f, 0.92387953251f, 0.70710678119f, 0.38268343236f, 0.f, -0.38268343236f, -0.70710678119f, -0.92387953251f};
        constexpr float c8s[8] = {0.f, -0.38268343236f, -0.70710678119f, -0.92387953251f, -1.f, -0.92387953251f, -0.70710678119f, -0.38268343236f};
        #pragma unroll
        for (int m = 0; m < 8; ++m){
            float2 tw = cmul(make_float2(c8c[m], c8s[m]), w);
            float2 u = v[m], t = v[m+8];
            v[m] = cadd(u,t);
            v[m+8] = cmul(csub(u,t), tw);
        }
    }
    w = cmul(w,w);
    {   constexpr float c4c[4] = {1.f, 0.70710678119f, 0.f, -0.70710678119f};
        constexpr float c4s[4] = {0.f, -0.70710678119f, -1.f, -0.70710678119f};
        #pragma unroll
        for (int h = 0; h < 16; h += 8)
            #pragma unroll
            for (int m = 0; m < 4; ++m){
                float2 tw = cmul(make_float2(c4c[m], c4s[m]), w);
                float2 u = v[h+m], t = v[h+m+4];
                v[h+m] = cadd(u,t);
                v[h+m+4] = cmul(csub(u,t), tw);
            }
    }
    w = cmul(w,w);
    #pragma unroll
    for (int q = 0; q < 16; q += 4)
        #pragma unroll
        for (int m = 0; m < 2; ++m){
            float2 tw = (m == 0) ? w : make_float2(w.y, -w.x);   // (-i)*w
            float2 u = v[q+m], t = v[q+m+2];
            v[q+m] = cadd(u,t);
            v[q+m+2] = cmul(csub(u,t), tw);
        }
    w = cmul(w,w);
    #pragma unroll
    for (int e = 0; e < 16; e += 2){
        float2 u = v[e], t = v[e+1];
        v[e] = cadd(u,t);
        v[e+1] = cmul(csub(u,t), w);
    }
}

// ---- 4 radix-2 DIT (inverse, +i) stages in registers.
__device__ __forceinline__ void dit_pass4(float2 v[16], float2 w3){
    float2 w2 = cmul(w3,w3), w1 = cmul(w2,w2), w0 = cmul(w1,w1);
    #pragma unroll
    for (int e = 0; e < 16; e += 2){
        float2 t = cmul(v[e+1], w0);
        float2 u = v[e];
        v[e] = cadd(u,t); v[e+1] = csub(u,t);
    }
    #pragma unroll
    for (int q = 0; q < 16; q += 4)
        #pragma unroll
        for (int m = 0; m < 2; ++m){
            float2 tw = (m == 0) ? w1 : make_float2(-w1.y, w1.x); // (+i)*w
            float2 t = cmul(v[q+m+2], tw);
            float2 u = v[q+m];
            v[q+m] = cadd(u,t); v[q+m+2] = csub(u,t);
        }
    {   constexpr float c4c[4] = {1.f, 0.70710678119f, 0.f, -0.70710678119f};
        constexpr float c4s[4] = {0.f, 0.70710678119f, 1.f, 0.70710678119f};
        #pragma unroll
        for (int h = 0; h < 16; h += 8)
            #pragma unroll
            for (int m = 0; m < 4; ++m){
                float2 tw = cmul(make_float2(c4c[m], c4s[m]), w2);
                float2 t = cmul(v[h+m+4], tw);
                float2 u = v[h+m];
                v[h+m] = cadd(u,t); v[h+m+4] = csub(u,t);
            }
    }
    {   constexpr float c8c[8] = {1.f, 0.92387953251f, 0.70710678119f, 0.38268343236f, 0.f, -0.38268343236f, -0.70710678119f, -0.92387953251f};
        constexpr float c8s[8] = {0.f, 0.38268343236f, 0.70710678119f, 0.92387953251f, 1.f, 0.92387953251f, 0.70710678119f, 0.38268343236f};
        #pragma unroll
        for (int m = 0; m < 8; ++m){
            float2 tw = cmul(make_float2(c8c[m], c8s[m]), w3);
            float2 t = cmul(v[m+8], tw);
            float2 u = v[m];
            v[m] = cadd(u,t); v[m+8] = csub(u,t);
        }
    }
}

// forward stages 0..11 on LDS (leaves stage-11 output in LDS, bitrev-pending)
__device__ __forceinline__ void fwd_fft12(float2* z, int tid){
    float2 v[16];
    float sn, cs;
    __sincosf(-(float)M_PI * (float)tid * (1.0f/4096.0f), &sn, &cs);
    float2 base = make_float2(cs, sn);
    #pragma unroll
    for (int k = 0; k < 16; ++k) v[k] = z[SW((k<<9) | tid)];
    dif_pass4(v, base);
    #pragma unroll
    for (int k = 0; k < 16; ++k) z[SW((k<<9) | tid)] = v[k];
    __syncthreads();
    const int hi = tid >> 5, lo = tid & 31;
    __sincosf(-(float)M_PI * (float)lo * (1.0f/256.0f), &sn, &cs);
    base = make_float2(cs, sn);
    #pragma unroll
    for (int k = 0; k < 16; ++k) v[k] = z[SW((hi<<9) | (k<<5) | lo)];
    dif_pass4(v, base);
    #pragma unroll
    for (int k = 0; k < 16; ++k) z[SW((hi<<9) | (k<<5) | lo)] = v[k];
    __syncthreads();
    const int h2 = tid >> 1, b0 = tid & 1;
    base = b0 ? make_float2(0.98078528040f, -0.19509032202f)   // exp(-i pi/16)
              : make_float2(1.f, 0.f);
    #pragma unroll
    for (int k = 0; k < 16; ++k) v[k] = z[SW((h2<<5) | (k<<1) | b0)];
    dif_pass4(v, base);
    #pragma unroll
    for (int k = 0; k < 16; ++k) z[SW((h2<<5) | (k<<1) | b0)] = v[k];
    __syncthreads();
}

// real-FFT untangle: from Z[rev(p)], Z[rev(N-p)] produce A=E+tO, G=E-tO
__device__ __forceinline__ void untangle(float2 zk, float2 znk, float2 t, float2& A, float2& G){
    float2 E  = make_float2(0.5f*(zk.x+znk.x), 0.5f*(zk.y-znk.y));
    float2 O  = make_float2(0.5f*(zk.y+znk.y), -0.5f*(zk.x-znk.x));
    float2 tO = cmul(t, O);
    A = cadd(E, tO); G = csub(E, tO);
}

// untangle x, multiply with H (Ah,Gh), repack packed-inverse spectrum pair
__device__ __forceinline__ void pointmul(float2 zk, float2 znk, float2 t,
                                         float2 Ah, float2 Gh, float invN,
                                         float2& Wp, float2& Wm){
    float2 Xp, Xm; untangle(zk, znk, t, Xp, Xm);
    float2 Cp = cmul(Ah, Xp), Cm = cmul(Gh, Xm);
    float2 S  = make_float2(0.5f*(Cp.x+Cm.x), 0.5f*(Cp.y+Cm.y));
    float2 Dd = make_float2(0.5f*(Cp.x-Cm.x), 0.5f*(Cp.y-Cm.y));
    float2 u  = make_float2(t.y*Dd.x - t.x*Dd.y, t.y*Dd.y + t.x*Dd.x); // i*conj(t)*Dd
    Wp = make_float2((S.x+u.x)*invN, (S.y+u.y)*invN);
    Wm = make_float2((S.x-u.x)*invN, -((S.y-u.y)*invN));
}

// ===================== kernel A: H spectra, once per d =====================
__global__ __launch_bounds__(NTHR)
void h_spec_kernel(const float* __restrict__ h,
                   float4* __restrict__ p0, float4* __restrict__ p1,
                   float2* __restrict__ hs2)
{
    __shared__ float2 z[FFT_N];
    const int tid = (int)threadIdx.x;
    const int d   = (int)blockIdx.x;
    const float2* hrow = (const float2*)(h + (size_t)d * SEQ_L);

    #pragma unroll
    for (int j = 0; j < 8; ++j){
        int n = tid + NTHR * j;
        z[SW(n)] = hrow[n];
        z[SW(n + FFT_N/2)] = make_float2(0.f, 0.f);
    }
    __syncthreads();
    fwd_fft12(z, tid);

    const size_t base = (size_t)d * 2048;
    #pragma unroll
    for (int q = 0; q < 4; ++q){
        int g = tid + NTHR * q;
        float2 A1, G1, A2, G2;
        if (g == 0){
            float2 z0 = z[SW(0)], z1 = z[SW(1)], z2 = z[SW(2)], z3 = z[SW(3)];
            float2 Z0 = cadd(z0,z1), Z1 = csub(z0,z1), Z2 = cadd(z2,z3), Z3 = csub(z2,z3);
            float2 A3, G3;
            untangle(Z0, Z0, make_float2(1.f, 0.f), A1, G1);                        // p=0
            untangle(Z2, Z3, make_float2(0.70710678119f, -0.70710678119f), A2, G2); // p=2048
            untangle(Z1, Z1, make_float2(0.f, -1.f), A3, G3);                       // p=4096
            hs2[(size_t)d*2 + 0] = A3;
            hs2[(size_t)d*2 + 1] = G3;
        } else {
            int a = rev13(g), c = rev13(4096 - g);
            float2 za = z[SW(a)], zb = z[SW(a+1)], zc = z[SW(c)], zd = z[SW(c+1)];
            float2 Z12a = cadd(za,zb), Z12b = csub(za,zb);
            float2 Z12c = cadd(zc,zd), Z12d = csub(zc,zd);
            float sn, cs; __sincosf(-(float)M_PI * (float)g * (1.0f/8192.0f), &sn, &cs);
            float2 t1 = make_float2(cs, sn), t2 = make_float2(-sn, -cs);
            untangle(Z12a, Z12d, t1, A1, G1);   // pair (g, 8192-g)
            untangle(Z12c, Z12b, t2, A2, G2);   // pair (4096-g, 4096+g)
        }
        p0[base + q*NTHR + tid] = make_float4(A1.x, A1.y, G1.x, G1.y);
        p1[base + q*NTHR + tid] = make_float4(A2.x, A2.y, G2.x, G2.y);
    }
}

// ===================== kernel B: x FFT + pointwise + inverse =====================
__global__ __launch_bounds__(NTHR)
void fftconv_x_kernel(const float* __restrict__ x,
                      const float* __restrict__ Bv,
                      float* __restrict__ y,
                      const float4* __restrict__ p0, const float4* __restrict__ p1,
                      const float2* __restrict__ hs2)
{
    __shared__ float2 z[FFT_N];
    const int tid = (int)threadIdx.x;
    const int d   = (int)blockIdx.x;
    const int b   = (int)blockIdx.y;

    const float Bd = Bv[d];
    const float2* xrow = (const float2*)(x + ((size_t)b * DIM_D + (size_t)d) * SEQ_L);
    float2*       yrow = (float2*)(y + ((size_t)b * DIM_D + (size_t)d) * SEQ_L);
    const float invN = 1.0f / (float)FFT_N;

    #pragma unroll
    for (int j = 0; j < 8; ++j){
        int n = tid + NTHR * j;
        z[SW(n)] = xrow[n];
        z[SW(n + FFT_N/2)] = make_float2(0.f, 0.f);
    }
    __syncthreads();
    fwd_fft12(z, tid);

    // fused middle: fwd stage12 + untangle + multiply + repack + inv stage0.
    const size_t base = (size_t)d * 2048;
    #pragma unroll
    for (int q = 0; q < 4; ++q){
        int g = tid + NTHR * q;
        float4 f0 = p0[base + q*NTHR + tid];
        float4 f1 = p1[base + q*NTHR + tid];
        float2 Ah1 = make_float2(f0.x, f0.y), Gh1 = make_float2(f0.z, f0.w);
        float2 Ah2 = make_float2(f1.x, f1.y), Gh2 = make_float2(f1.z, f1.w);
        if (g == 0){
            float2 A3 = hs2[(size_t)d*2 + 0], G3 = hs2[(size_t)d*2 + 1];
            float2 z0 = z[SW(0)], z1 = z[SW(1)], z2 = z[SW(2)], z3 = z[SW(3)];
            float2 Z0 = cadd(z0,z1), Z1 = csub(z0,z1), Z2 = cadd(z2,z3), Z3 = csub(z2,z3);
            float2 W0, W0b, W1, W1b, W2, W3;
            pointmul(Z0, Z0, make_float2(1.f, 0.f),  Ah1, Gh1, invN, W0, W0b);
            pointmul(Z1, Z1, make_float2(0.f, -1.f), A3,  G3,  invN, W1, W1b);
            pointmul(Z2, Z3, make_float2(0.70710678119f, -0.70710678119f), Ah2, Gh2, invN, W2, W3);
            z[SW(0)] = cadd(W0, W1);
            z[SW(1)] = csub(W0, W1);
            z[SW(2)] = cadd(W2, W3);
            z[SW(3)] = csub(W2, W3);
        } else {
            int a = rev13(g), c = rev13(4096 - g);
            float2 za = z[SW(a)], zb = z[SW(a+1)], zc = z[SW(c)], zd = z[SW(c+1)];
            float2 Z12a = cadd(za,zb), Z12b = csub(za,zb);
            float2 Z12c = cadd(zc,zd), Z12d = csub(zc,zd);
            float sn, cs; __sincosf(-(float)M_PI * (float)g * (1.0f/8192.0f), &sn, &cs);
            float2 t1 = make_float2(cs, sn), t2 = make_float2(-sn, -cs);
            float2 Wp1, Wm1, Wp2, Wm2;
            pointmul(Z12a, Z12d, t1, Ah1, Gh1, invN, Wp1, Wm1);
            pointmul(Z12c, Z12b, t2, Ah2, Gh2, invN, Wp2, Wm2);
            z[SW(a)]   = cadd(Wp1, Wm2);
            z[SW(a+1)] = csub(Wp1, Wm2);
            z[SW(c)]   = cadd(Wp2, Wm1);
            z[SW(c+1)] = csub(Wp2, Wm1);
        }
    }
    __syncthreads();

    // inverse stages 1..12
    {
        float2 v[16];
        float sn, cs;
        const int h2 = tid >> 1, b0 = tid & 1, hi = tid >> 5, lo = tid & 31;
        float2 w3 = b0 ? make_float2(0.98078528040f, 0.19509032202f)  // exp(+i pi/16)
                       : make_float2(1.f, 0.f);
        #pragma unroll
        for (int k = 0; k < 16; ++k) v[k] = z[SW((h2<<5) | (k<<1) | b0)];
        dit_pass4(v, w3);
        #pragma unroll
        for (int k = 0; k < 16; ++k) z[SW((h2<<5) | (k<<1) | b0)] = v[k];
        __syncthreads();
        __sincosf((float)M_PI * (float)lo * (1.0f/256.0f), &sn, &cs);
        w3 = make_float2(cs, sn);
        #pragma unroll
        for (int k = 0; k < 16; ++k) v[k] = z[SW((hi<<9) | (k<<5) | lo)];
        dit_pass4(v, w3);
        #pragma unroll
        for (int k = 0; k < 16; ++k) z[SW((hi<<9) | (k<<5) | lo)] = v[k];
        __syncthreads();
        __sincosf((float)M_PI * (float)tid * (1.0f/4096.0f), &sn, &cs);
        w3 = make_float2(cs, sn);
        #pragma unroll
        for (int k = 0; k < 16; ++k) v[k] = z[SW((k<<9) | tid)];
        dit_pass4(v, w3);
        #pragma unroll
        for (int k = 0; k < 16; ++k) z[SW((k<<9) | tid)] = v[k];
        __syncthreads();
    }

    #pragma unroll
    for (int j = 0; j < 8; ++j){
        int n = tid + NTHR * j;
        float2 wv = z[SW(n)];
        float2 xv = xrow[n];
        yrow[n] = make_float2(wv.x + xv.x * Bd, wv.y + xv.y * Bd);
    }
}

// ============== fallback: single fused kernel (if ws too small) ==============
__global__ __launch_bounds__(NTHR)
void fftconv_fused(const float* __restrict__ h,
                   const float* __restrict__ x,
                   const float* __restrict__ Bv,
                   float* __restrict__ y)
{
    __shared__ float2 z[FFT_N];
    const int tid = (int)threadIdx.x;
    const int d   = (int)blockIdx.x;
    const int b   = (int)blockIdx.y;

    const float Bd = Bv[d];
    const float2* hrow = (const float2*)(h + (size_t)d * SEQ_L);
    const float2* xrow = (const float2*)(x + ((size_t)b * DIM_D + (size_t)d) * SEQ_L);
    float2*       yrow = (float2*)(y + ((size_t)b * DIM_D + (size_t)d) * SEQ_L);
    const float invN = 1.0f / (float)FFT_N;

    #pragma unroll
    for (int j = 0; j < 8; ++j){
        int n = tid + NTHR * j;
        z[SW(n)] = hrow[n];
        z[SW(n + FFT_N/2)] = make_float2(0.f, 0.f);
    }
    __syncthreads();
    fwd_fft12(z, tid);

    float2 Ah1[4], Gh1[4], Ah2[4], Gh2[4], Ah3, Gh3;
    #pragma unroll
    for (int q = 0; q < 4; ++q){
        int g = tid + NTHR * q;
        if (g == 0){
            float2 z0 = z[SW(0)], z1 = z[SW(1)], z2 = z[SW(2)], z3 = z[SW(3)];
            float2 Z0 = cadd(z0,z1), Z1 = csub(z0,z1), Z2 = cadd(z2,z3), Z3 = csub(z2,z3);
            untangle(Z0, Z0, make_float2(1.f, 0.f), Ah1[0], Gh1[0]);
            untangle(Z2, Z3, make_float2(0.70710678119f, -0.70710678119f), Ah2[0], Gh2[0]);
            untangle(Z1, Z1, make_float2(0.f, -1.f), Ah3, Gh3);
        } else {
            int a = rev13(g), c = rev13(4096 - g);
            float2 za = z[SW(a)], zb = z[SW(a+1)], zc = z[SW(c)], zd = z[SW(c+1)];
            float2 Z12a = cadd(za,zb), Z12b = csub(za,zb);
            float2 Z12c = cadd(zc,zd), Z12d = csub(zc,zd);
            float sn, cs; __sincosf(-(float)M_PI * (float)g * (1.0f/8192.0f), &sn, &cs);
            float2 t1 = make_float2(cs, sn), t2 = make_float2(-sn, -cs);
            untangle(Z12a, Z12d, t1, Ah1[q], Gh1[q]);
            untangle(Z12c, Z12b, t2, Ah2[q], Gh2[q]);
        }
    }
    __syncthreads();

    #pragma unroll
    for (int j = 0; j < 8; ++j){
        int n = tid + NTHR * j;
        z[SW(n)] = xrow[n];
        z[SW(n + FFT_N/2)] = make_float2(0.f, 0.f);
    }
    __syncthreads();
    fwd_fft12(z, tid);

    #pragma unroll
    for (int q = 0; q < 4; ++q){
        int g = tid + NTHR * q;
        if (g == 0){
            float2 z0 = z[SW(0)], z1 = z[SW(1)], z2 = z[SW(2)], z3 = z[SW(3)];
            float2 Z0 = cadd(z0,z1), Z1 = csub(z0,z1), Z2 = cadd(z2,z3), Z3 = csub(z2,z3);
            float2 W0, W0b, W1, W1b, W2, W3;
            pointmul(Z0, Z0, make_float2(1.f, 0.f),  Ah1[0], Gh1[0], invN, W0, W0b);
            pointmul(Z1, Z1, make_float2(0.f, -1.f), Ah3,    Gh3,    invN, W1, W1b);
            pointmul(Z2, Z3, make_float2(0.70710678119f, -0.70710678119f), Ah2[0], Gh2[0], invN, W2, W3);
            z[SW(0)] = cadd(W0, W1);
            z[SW(1)] = csub(W0, W1);
            z[SW(2)] = cadd(W2, W3);
            z[SW(3)] = csub(W2, W3);
        } else {
            int a = rev13(g), c = rev13(4096 - g);
            float2 za = z[SW(a)], zb = z[SW(a+1)], zc = z[SW(c)], zd = z[SW(c+1)];
            float2 Z12a = cadd(za,zb), Z12b = csub(za,zb);
            float2 Z12c = cadd(zc,zd), Z12d = csub(zc,zd);
            float sn, cs; __sincosf(-(float)M_PI * (float)g * (1.0f/8192.0f), &sn, &cs);
            float2 t1 = make_float2(cs, sn), t2 = make_float2(-sn, -cs);
            float2 Wp1, Wm1, Wp2, Wm2;
            pointmul(Z12a, Z12d, t1, Ah1[q], Gh1[q], invN, Wp1, Wm1);
            pointmul(Z12c, Z12b, t2, Ah2[q], Gh2[q], invN, Wp2, Wm2);
            z[SW(a)]   = cadd(Wp1, Wm2);
            z[SW(a+1)] = csub(Wp1, Wm2);
            z[SW(c)]   = cadd(Wp2, Wm1);
            z[SW(c+1)] = csub(Wp2, Wm1);
        }
    }
    __syncthreads();

    {
        float2 v[16];
        float sn, cs;
        const int h2 = tid >> 1, b0 = tid & 1, hi = tid >> 5, lo = tid & 31;
        float2 w3 = b0 ? make_float2(0.98078528040f, 0.19509032202f)
                       : make_float2(1.f, 0.f);
        #pragma unroll
        for (int k = 0; k < 16; ++k) v[k] = z[SW((h2<<5) | (k<<1) | b0)];
        dit_pass4(v, w3);
        #pragma unroll
        for (int k = 0; k < 16; ++k) z[SW((h2<<5) | (k<<1) | b0)] = v[k];
        __syncthreads();
        __sincosf((float)M_PI * (float)lo * (1.0f/256.0f), &sn, &cs);
        w3 = make_float2(cs, sn);
        #pragma unroll
        for (int k = 0; k < 16; ++k) v[k] = z[SW((hi<<9) | (k<<5) | lo)];
        dit_pass4(v, w3);
        #pragma unroll
        for (int k = 0; k < 16; ++k) z[SW((hi<<9) | (k<<5) | lo)] = v[k];
        __syncthreads();
        __sincosf((float)M_PI * (float)tid * (1.0f/4096.0f), &sn, &cs);
        w3 = make_float2(cs, sn);
        #pragma unroll
        for (int k = 0; k < 16; ++k) v[k] = z[SW((k<<9) | tid)];
        dit_pass4(v, w3);
        #pragma unroll
        for (int k = 0; k < 16; ++k) z[SW((k<<9) | tid)] = v[k];
        __syncthreads();
    }

    #pragma unroll
    for (int j = 0; j < 8; ++j){
        int n = tid + NTHR * j;
        float2 wv = z[SW(n)];
        float2 xv = xrow[n];
        yrow[n] = make_float2(wv.x + xv.x * Bd, wv.y + xv.y * Bd);
    }
}

extern "C" void kernel_launch(void* const* d_in, const int* in_sizes, int n_in,
                              void* d_out, int out_size, void* d_ws, size_t ws_size,
                              hipStream_t stream) {
    const float* h  = (const float*)d_in[0];
    const float* x  = (const float*)d_in[1];
    const float* Bv = (const float*)d_in[2];
    float* y = (float*)d_out;

    const int bsz = out_size / (DIM_D * SEQ_L);   // = 4
    const size_t plane = (size_t)DIM_D * 2048;    // float4 elements per plane
    const size_t need  = plane * 2 * sizeof(float4) + (size_t)DIM_D * 2 * sizeof(float2);

    if (ws_size >= need) {
        float4* p0  = (float4*)d_ws;
        float4* p1  = p0 + plane;
        float2* hs2 = (float2*)(p1 + plane);
        hipLaunchKernelGGL(h_spec_kernel, dim3(DIM_D), dim3(NTHR), 0, stream, h, p0, p1, hs2);
        hipLaunchKernelGGL(fftconv_x_kernel, dim3(DIM_D, bsz), dim3(NTHR), 0, stream,
                           x, Bv, y, p0, p1, hs2);
    } else {
        hipLaunchKernelGGL(fftconv_fused, dim3(DIM_D, bsz), dim3(NTHR), 0, stream, h, x, Bv, y);
    }
}